// Round 6
// baseline (4904.602 us; speedup 1.0000x reference)
//
#include <hip/hip_runtime.h>

#define N_NODES 100000
#define N_EDGES 1600000
#define F_IN 512
#define F_HID 128
#define F_OUT 64

__device__ float g6_bf2f(unsigned short u) {
    return __uint_as_float(((unsigned int)u) << 16);
}

__device__ unsigned short g6_f2bf(float f) {
    unsigned int u = __float_as_uint(f);
    u = u + 0x7fffu + ((u >> 16) & 1u);
    return (unsigned short)(u >> 16);
}

__global__ void GCN_16716012716713_kernel() {}

__global__ void g6_zero(float* p, int n) {
    int i = blockIdx.x * blockDim.x + threadIdx.x;
    if (i < n) p[i] = 0.0f;
}

// edge_index dtype probe: 1=int32, 0=int64 (int64 has all-zero high words)
__global__ void g6_iprobe(const int* raw, int* iflag) {
    if (blockIdx.x == 0 && threadIdx.x == 0) {
        int f = 0;
        for (int i = 0; i < 1024; i = i + 1) {
            if (raw[2 * i + 1] != 0) f = 1;
        }
        iflag[0] = f;
    }
}

// float dtype probe on x: 1=bf16, 0=fp32 (see r5 notes)
__global__ void g6_fprobe(const unsigned int* xw, int* fflag) {
    if (blockIdx.x == 0 && threadIdx.x == 0) {
        int cnt = 0;
        for (int i = 0; i < 4096; i = i + 1) {
            unsigned int lo = xw[i] & 0xffffu;
            unsigned int e = (lo >> 7) & 0xffu;
            if (e >= 110u && e <= 140u) cnt = cnt + 1;
        }
        fflag[0] = (cnt > 2048) ? 1 : 0;
    }
}

__global__ void g6_pack(const int* raw, const int* iflag, int* ei) {
    int i = blockIdx.x * blockDim.x + threadIdx.x;
    if (i < 2 * N_EDGES) {
        if (iflag[0] == 0) {
            ei[i] = raw[2 * i];
        } else {
            ei[i] = raw[i];
        }
    }
}

__global__ void g6_cvt(const void* src, const int* fflag, float* dst, int n) {
    int i = blockIdx.x * blockDim.x + threadIdx.x;
    if (i < n) {
        if (fflag[0] == 1) {
            dst[i] = g6_bf2f(((const unsigned short*)src)[i]);
        } else {
            dst[i] = ((const float*)src)[i];
        }
    }
}

__global__ void g6_deg(const int* ei, int* deg) {
    int e = blockIdx.x * blockDim.x + threadIdx.x;
    if (e < N_EDGES) {
        atomicAdd(&deg[ei[N_EDGES + e]], 1);
    }
}

__global__ void g6_dinv(const int* deg, float* dinv) {
    int i = blockIdx.x * blockDim.x + threadIdx.x;
    if (i < N_NODES) {
        dinv[i] = rsqrtf((float)deg[i] + 1.0f);
    }
}

// ---- GEMM1: h1[100000,128] = x[100000,512] @ W1f. BM=64, BN=128, BK=16,
// 256 threads, 8x4 micro-tile. W1 staged in LDS once per 64 rows (kills the
// 26 GB L2 W-restream that made r5's gemm1 955us). ----
__global__ void g6_gemm1(const void* x, const int* fflag, const float* W,
                         float* h1) {
    __shared__ float Xs[16][68];   // +4 pad: 16B-aligned rows, conflict-free stores
    __shared__ float Ws[16][128];
    int tid = threadIdx.x;
    int m0 = blockIdx.x * 64;
    int tx = tid & 31;   // cols tx*4 .. tx*4+3
    int ty = tid >> 5;   // rows ty*8 .. ty*8+7
    int isbf = fflag[0];
    float acc[8][4];
#pragma unroll
    for (int i = 0; i < 8; ++i) {
#pragma unroll
        for (int j = 0; j < 4; ++j) acc[i][j] = 0.0f;
    }

    for (int k0 = 0; k0 < F_IN; k0 += 16) {
        // stage X tile (64 rows x 16 k), transposed into Xs[k][m]
        int kk = tid & 15;
        int mm = tid >> 4;   // 0..15
#pragma unroll
        for (int r = 0; r < 4; ++r) {
            int m = m0 + mm + r * 16;
            float v = 0.0f;
            if (m < N_NODES) {
                long long gi = (long long)m * F_IN + k0 + kk;
                if (isbf == 1) {
                    v = g6_bf2f(((const unsigned short*)x)[gi]);
                } else {
                    v = ((const float*)x)[gi];
                }
            }
            Xs[kk][mm + r * 16] = v;
        }
        // stage W tile (16 k x 128 n)
#pragma unroll
        for (int r = 0; r < 8; ++r) {
            int i = r * 256 + tid;
            int wk = i >> 7;
            int wn = i & 127;
            Ws[wk][wn] = W[(k0 + wk) * F_HID + wn];
        }
        __syncthreads();
#pragma unroll
        for (int k = 0; k < 16; ++k) {
            float a[8];
            float b[4];
#pragma unroll
            for (int i = 0; i < 8; ++i) a[i] = Xs[k][ty * 8 + i];
#pragma unroll
            for (int j = 0; j < 4; ++j) b[j] = Ws[k][tx * 4 + j];
#pragma unroll
            for (int i = 0; i < 8; ++i) {
#pragma unroll
                for (int j = 0; j < 4; ++j) acc[i][j] += a[i] * b[j];
            }
        }
        __syncthreads();
    }
#pragma unroll
    for (int i = 0; i < 8; ++i) {
        int m = m0 + ty * 8 + i;
        if (m < N_NODES) {
            float4 o;
            o.x = acc[i][0]; o.y = acc[i][1]; o.z = acc[i][2]; o.w = acc[i][3];
            *(float4*)(h1 + (long long)m * F_HID + tx * 4) = o;
        }
    }
}

// ---- agg1: agg1[d, g*4..] += h1[s, g*4..] * dinv[s]*dinv[d]; float4 gather ----
__global__ void g6_agg1(const int* ei, const float* dinv, const float* h1,
                        float* agg1) {
    long long t = (long long)blockIdx.x * blockDim.x + threadIdx.x;
    if (t < (long long)N_EDGES * 32) {
        int e = (int)(t >> 5);
        int g = (int)(t & 31);
        int s = ei[e];
        int d = ei[N_EDGES + e];
        float nrm = dinv[s] * dinv[d];
        float4 v = *(const float4*)(h1 + (long long)s * F_HID + g * 4);
        float* o = agg1 + (long long)d * F_HID + g * 4;
        atomicAdd(o + 0, v.x * nrm);
        atomicAdd(o + 1, v.y * nrm);
        atomicAdd(o + 2, v.z * nrm);
        atomicAdd(o + 3, v.w * nrm);
    }
}

// ---- GEMM2: r1 = relu(agg1 + h1*dinv^2 + b1) computed in staging;
// h2[100000,64] = r1 @ W2f. BM=64, BN=64, BK=32, 256 threads, 4x4 micro. ----
__global__ void g6_gemm2(const float* agg1, const float* h1, const float* dinv,
                         const float* b1, const float* W2, float* h2) {
    __shared__ float Rs[32][68];   // +4 pad
    __shared__ float Ws[32][64];
    int tid = threadIdx.x;
    int m0 = blockIdx.x * 64;
    int tx = tid & 15;   // cols tx*4
    int ty = tid >> 4;   // rows ty*4
    float acc[4][4];
#pragma unroll
    for (int i = 0; i < 4; ++i) {
#pragma unroll
        for (int j = 0; j < 4; ++j) acc[i][j] = 0.0f;
    }

    for (int k0 = 0; k0 < F_HID; k0 += 32) {
        // stage Rs (64 m x 32 k) with fused layer-1 epilogue
#pragma unroll
        for (int r = 0; r < 8; ++r) {
            int i = r * 256 + tid;
            int kk = i & 31;
            int mm = i >> 5;
            int m = m0 + mm;
            float v = 0.0f;
            if (m < N_NODES) {
                long long gi = (long long)m * F_HID + k0 + kk;
                float s = dinv[m];
                v = agg1[gi] + h1[gi] * s * s + b1[k0 + kk];
                if (v < 0.0f) v = 0.0f;
            }
            Rs[kk][mm] = v;
        }
        // stage W2 (32 k x 64 n)
#pragma unroll
        for (int r = 0; r < 8; ++r) {
            int i = r * 256 + tid;
            int wk = i >> 6;
            int wn = i & 63;
            Ws[wk][wn] = W2[(k0 + wk) * F_OUT + wn];
        }
        __syncthreads();
#pragma unroll
        for (int k = 0; k < 32; ++k) {
            float a[4];
            float b[4];
#pragma unroll
            for (int i = 0; i < 4; ++i) a[i] = Rs[k][ty * 4 + i];
#pragma unroll
            for (int j = 0; j < 4; ++j) b[j] = Ws[k][tx * 4 + j];
#pragma unroll
            for (int i = 0; i < 4; ++i) {
#pragma unroll
                for (int j = 0; j < 4; ++j) acc[i][j] += a[i] * b[j];
            }
        }
        __syncthreads();
    }
#pragma unroll
    for (int i = 0; i < 4; ++i) {
        int m = m0 + ty * 4 + i;
        if (m < N_NODES) {
            float4 o;
            o.x = acc[i][0]; o.y = acc[i][1]; o.z = acc[i][2]; o.w = acc[i][3];
            *(float4*)(h2 + (long long)m * F_OUT + tx * 4) = o;
        }
    }
}

// ---- agg2: float4 version, F=64 ----
__global__ void g6_agg2(const int* ei, const float* dinv, const float* h2,
                        float* agg2) {
    long long t = (long long)blockIdx.x * blockDim.x + threadIdx.x;
    if (t < (long long)N_EDGES * 16) {
        int e = (int)(t >> 4);
        int g = (int)(t & 15);
        int s = ei[e];
        int d = ei[N_EDGES + e];
        float nrm = dinv[s] * dinv[d];
        float4 v = *(const float4*)(h2 + (long long)s * F_OUT + g * 4);
        float* o = agg2 + (long long)d * F_OUT + g * 4;
        atomicAdd(o + 0, v.x * nrm);
        atomicAdd(o + 1, v.y * nrm);
        atomicAdd(o + 2, v.z * nrm);
        atomicAdd(o + 3, v.w * nrm);
    }
}

// ---- final: out = (agg2 + h2*dinv^2 + b2), stored in the input float format ----
__global__ void g6_final(const float* agg2, const float* h2, const float* dinv,
                         const float* b2, const int* fflag, void* out) {
    int idx = blockIdx.x * blockDim.x + threadIdx.x;
    if (idx < N_NODES * F_OUT) {
        int m = idx >> 6;
        int n = idx & 63;
        float s2 = dinv[m] * dinv[m];
        float v = agg2[idx] + h2[idx] * s2 + b2[n];
        if (fflag[0] == 1) {
            ((unsigned short*)out)[idx] = g6_f2bf(v);
        } else {
            ((float*)out)[idx] = v;
        }
    }
}

extern "C" void kernel_launch(void* const* d_in, const int* in_sizes, int n_in,
                              void* d_out, int out_size, void* d_ws, size_t ws_size,
                              hipStream_t stream) {
    const void* x     = d_in[0];
    const int* ei_raw = (const int*)d_in[1];
    const void* W1    = d_in[2];
    const void* b1    = d_in[3];
    const void* W2    = d_in[4];
    const void* b2    = d_in[5];

    // workspace layout (byte offsets, 16B-aligned), identical to round 5 (proven):
    char* ws = (char*)d_ws;
    int*   deg   = (int*)(ws + 0);            //    400,000 B
    int*   iflag = (int*)(ws + 409600);       //          4 B
    int*   fflag = (int*)(ws + 409616);       //          4 B
    float* dinv  = (float*)(ws + 524288);     //    400,000 B
    float* W1f   = (float*)(ws + 1048576);    //    262,144 B
    float* b1f   = (float*)(ws + 1310720);    //        512 B
    float* W2f   = (float*)(ws + 1311232);    //     32,768 B
    float* b2f   = (float*)(ws + 1344000);    //        256 B
    int*   ei    = (int*)(ws + 2097152);      // 12,800,000 B
    float* h1    = (float*)(ws + 16777216);   // 51,200,000 B
    float* agg1  = (float*)(ws + 68157440);   // 51,200,000 B
    float* h2    = (float*)(ws + 119537664);  // 25,600,000 B
    float* agg2  = (float*)(ws + 146800640);  // 25,600,000 B

    g6_zero<<<(N_NODES + 255) / 256, 256, 0, stream>>>((float*)deg, N_NODES);
    g6_zero<<<(N_NODES * F_HID + 255) / 256, 256, 0, stream>>>(agg1, N_NODES * F_HID);
    g6_zero<<<(N_NODES * F_OUT + 255) / 256, 256, 0, stream>>>(agg2, N_NODES * F_OUT);

    g6_iprobe<<<1, 64, 0, stream>>>(ei_raw, iflag);
    g6_fprobe<<<1, 64, 0, stream>>>((const unsigned int*)x, fflag);

    g6_pack<<<(2 * N_EDGES + 255) / 256, 256, 0, stream>>>(ei_raw, iflag, ei);

    g6_cvt<<<(F_IN * F_HID + 255) / 256, 256, 0, stream>>>(W1, fflag, W1f, F_IN * F_HID);
    g6_cvt<<<1, 128, 0, stream>>>(b1, fflag, b1f, F_HID);
    g6_cvt<<<(F_HID * F_OUT + 255) / 256, 256, 0, stream>>>(W2, fflag, W2f, F_HID * F_OUT);
    g6_cvt<<<1, 64, 0, stream>>>(b2, fflag, b2f, F_OUT);

    g6_deg<<<(N_EDGES + 255) / 256, 256, 0, stream>>>(ei, deg);
    g6_dinv<<<(N_NODES + 255) / 256, 256, 0, stream>>>(deg, dinv);

    g6_gemm1<<<(N_NODES + 63) / 64, 256, 0, stream>>>(x, fflag, W1f, h1);

    {
        long long total = (long long)N_EDGES * 32;
        int blocks = (int)((total + 255) / 256);
        g6_agg1<<<blocks, 256, 0, stream>>>(ei, dinv, h1, agg1);
    }

    g6_gemm2<<<(N_NODES + 63) / 64, 256, 0, stream>>>(agg1, h1, dinv, b1f, W2f, h2);

    {
        long long total = (long long)N_EDGES * 16;
        int blocks = (int)((total + 255) / 256);
        g6_agg2<<<blocks, 256, 0, stream>>>(ei, dinv, h2, agg2);
    }

    g6_final<<<(N_NODES * F_OUT + 255) / 256, 256, 0, stream>>>(agg2, h2, dinv, b2f, fflag, d_out);
}

// Round 7
// 1268.378 us; speedup vs baseline: 3.8668x; 3.8668x over previous
//
#include <hip/hip_runtime.h>

#define N_NODES 100000
#define N_EDGES 1600000
#define F_IN 512
#define F_HID 128
#define F_OUT 64

__device__ float g7_bf2f(unsigned short u) {
    return __uint_as_float(((unsigned int)u) << 16);
}

__device__ unsigned short g7_f2bf(float f) {
    unsigned int u = __float_as_uint(f);
    u = u + 0x7fffu + ((u >> 16) & 1u);
    return (unsigned short)(u >> 16);
}

__global__ void GCN_16716012716713_kernel() {}

__global__ void g7_zero(int* p, int n) {
    int i = blockIdx.x * blockDim.x + threadIdx.x;
    if (i < n) p[i] = 0;
}

// edge_index dtype probe: 1=int32, 0=int64 (int64 has all-zero high words)
__global__ void g7_iprobe(const int* raw, int* iflag) {
    if (blockIdx.x == 0 && threadIdx.x == 0) {
        int f = 0;
        for (int i = 0; i < 1024; i = i + 1) {
            if (raw[2 * i + 1] != 0) f = 1;
        }
        iflag[0] = f;
    }
}

// float dtype probe on x: 1=bf16, 0=fp32
__global__ void g7_fprobe(const unsigned int* xw, int* fflag) {
    if (blockIdx.x == 0 && threadIdx.x == 0) {
        int cnt = 0;
        for (int i = 0; i < 4096; i = i + 1) {
            unsigned int lo = xw[i] & 0xffffu;
            unsigned int e = (lo >> 7) & 0xffu;
            if (e >= 110u && e <= 140u) cnt = cnt + 1;
        }
        fflag[0] = (cnt > 2048) ? 1 : 0;
    }
}

__global__ void g7_pack(const int* raw, const int* iflag, int* ei) {
    int i = blockIdx.x * blockDim.x + threadIdx.x;
    if (i < 2 * N_EDGES) {
        if (iflag[0] == 0) {
            ei[i] = raw[2 * i];
        } else {
            ei[i] = raw[i];
        }
    }
}

__global__ void g7_cvt(const void* src, const int* fflag, float* dst, int n) {
    int i = blockIdx.x * blockDim.x + threadIdx.x;
    if (i < n) {
        if (fflag[0] == 1) {
            dst[i] = g7_bf2f(((const unsigned short*)src)[i]);
        } else {
            dst[i] = ((const float*)src)[i];
        }
    }
}

__global__ void g7_deg(const int* ei, int* deg) {
    int e = blockIdx.x * blockDim.x + threadIdx.x;
    if (e < N_EDGES) {
        atomicAdd(&deg[ei[N_EDGES + e]], 1);
    }
}

__global__ void g7_dinv(const int* deg, float* dinv) {
    int i = blockIdx.x * blockDim.x + threadIdx.x;
    if (i < N_NODES) {
        dinv[i] = rsqrtf((float)deg[i] + 1.0f);
    }
}

// ---- CSR build: block-sums -> serial scan of 391 block sums -> per-block scan ----
__global__ void g7_bsum(const int* deg, int* bsum) {
    __shared__ int s[256];
    int i = blockIdx.x * 256 + threadIdx.x;
    s[threadIdx.x] = (i < N_NODES) ? deg[i] : 0;
    __syncthreads();
    for (int off = 128; off > 0; off >>= 1) {
        if (threadIdx.x < off) s[threadIdx.x] += s[threadIdx.x + off];
        __syncthreads();
    }
    if (threadIdx.x == 0) bsum[blockIdx.x] = s[0];
}

__global__ void g7_bscan(const int* bsum, int* boff, int nblk, int* rowptr) {
    if (blockIdx.x == 0 && threadIdx.x == 0) {
        int acc = 0;
        for (int b = 0; b < nblk; b = b + 1) {
            boff[b] = acc;
            acc = acc + bsum[b];
        }
        rowptr[N_NODES] = acc;   // == N_EDGES
    }
}

__global__ void g7_scan(const int* deg, const int* boff, int* rowptr, int* cursor) {
    __shared__ int s[256];
    int i = blockIdx.x * 256 + threadIdx.x;
    int v = (i < N_NODES) ? deg[i] : 0;
    s[threadIdx.x] = v;
    __syncthreads();
    for (int off = 1; off < 256; off <<= 1) {
        int t = (threadIdx.x >= off) ? s[threadIdx.x - off] : 0;
        __syncthreads();
        s[threadIdx.x] += t;
        __syncthreads();
    }
    if (i < N_NODES) {
        int excl = s[threadIdx.x] - v + boff[blockIdx.x];
        rowptr[i] = excl;
        cursor[i] = excl;
    }
}

// scatter src ids into dst-grouped CSR order
__global__ void g7_scatter(const int* ei, int* cursor, int* csr) {
    int e = blockIdx.x * blockDim.x + threadIdx.x;
    if (e < N_EDGES) {
        int s = ei[e];
        int d = ei[N_EDGES + e];
        int pos = atomicAdd(&cursor[d], 1);
        csr[pos] = s;
    }
}

// ---- GEMM1: h1[100000,128] = x @ W1f. BM=64, BN=128, BK=16, 256 thr, 8x4 micro ----
__global__ void g7_gemm1(const void* x, const int* fflag, const float* W,
                         float* h1) {
    __shared__ float Xs[16][68];
    __shared__ float Ws[16][128];
    int tid = threadIdx.x;
    int m0 = blockIdx.x * 64;
    int tx = tid & 31;
    int ty = tid >> 5;
    int isbf = fflag[0];
    float acc[8][4];
#pragma unroll
    for (int i = 0; i < 8; ++i) {
#pragma unroll
        for (int j = 0; j < 4; ++j) acc[i][j] = 0.0f;
    }

    for (int k0 = 0; k0 < F_IN; k0 += 16) {
        int kk = tid & 15;
        int mm = tid >> 4;
#pragma unroll
        for (int r = 0; r < 4; ++r) {
            int m = m0 + mm + r * 16;
            float v = 0.0f;
            if (m < N_NODES) {
                long long gi = (long long)m * F_IN + k0 + kk;
                if (isbf == 1) {
                    v = g7_bf2f(((const unsigned short*)x)[gi]);
                } else {
                    v = ((const float*)x)[gi];
                }
            }
            Xs[kk][mm + r * 16] = v;
        }
#pragma unroll
        for (int r = 0; r < 8; ++r) {
            int i = r * 256 + tid;
            int wk = i >> 7;
            int wn = i & 127;
            Ws[wk][wn] = W[(k0 + wk) * F_HID + wn];
        }
        __syncthreads();
#pragma unroll
        for (int k = 0; k < 16; ++k) {
            float a[8];
            float b[4];
#pragma unroll
            for (int i = 0; i < 8; ++i) a[i] = Xs[k][ty * 8 + i];
#pragma unroll
            for (int j = 0; j < 4; ++j) b[j] = Ws[k][tx * 4 + j];
#pragma unroll
            for (int i = 0; i < 8; ++i) {
#pragma unroll
                for (int j = 0; j < 4; ++j) acc[i][j] += a[i] * b[j];
            }
        }
        __syncthreads();
    }
#pragma unroll
    for (int i = 0; i < 8; ++i) {
        int m = m0 + ty * 8 + i;
        if (m < N_NODES) {
            float4 o;
            o.x = acc[i][0]; o.y = acc[i][1]; o.z = acc[i][2]; o.w = acc[i][3];
            *(float4*)(h1 + (long long)m * F_HID + tx * 4) = o;
        }
    }
}

// ---- agg1 CSR: one wave per dst node, lane owns 2 features (float2).
// r1[d] = relu(dinv[d] * sum_e dinv[s]*h1[s] + dinv[d]^2 * h1[d] + b1). No atomics. ----
__global__ void g7_agg1(const int* rowptr, const int* csr, const float* dinv,
                        const float* h1, const float* b1, float* r1) {
    int node = blockIdx.x * 4 + (threadIdx.x >> 6);
    int lane = threadIdx.x & 63;
    if (node < N_NODES) {
        int beg = rowptr[node];
        int end = rowptr[node + 1];
        const float2* hv = (const float2*)h1;
        float ax = 0.0f;
        float ay = 0.0f;
        for (int j = beg; j < end; j = j + 1) {
            int s = csr[j];
            float w = dinv[s];
            float2 v = hv[(long long)s * 64 + lane];
            ax = ax + v.x * w;
            ay = ay + v.y * w;
        }
        float di = dinv[node];
        float2 hd = hv[(long long)node * 64 + lane];
        float rx = ax * di + hd.x * di * di + b1[2 * lane];
        float ry = ay * di + hd.y * di * di + b1[2 * lane + 1];
        if (rx < 0.0f) rx = 0.0f;
        if (ry < 0.0f) ry = 0.0f;
        float2 o;
        o.x = rx;
        o.y = ry;
        ((float2*)r1)[(long long)node * 64 + lane] = o;
    }
}

// ---- GEMM2: h2[100000,64] = r1 @ W2f. BM=64, BN=64, BK=32, 256 thr, 4x4 micro ----
__global__ void g7_gemm2(const float* r1, const float* W2, float* h2) {
    __shared__ float Rs[32][68];
    __shared__ float Ws[32][64];
    int tid = threadIdx.x;
    int m0 = blockIdx.x * 64;
    int tx = tid & 15;
    int ty = tid >> 4;
    float acc[4][4];
#pragma unroll
    for (int i = 0; i < 4; ++i) {
#pragma unroll
        for (int j = 0; j < 4; ++j) acc[i][j] = 0.0f;
    }

    for (int k0 = 0; k0 < F_HID; k0 += 32) {
#pragma unroll
        for (int r = 0; r < 8; ++r) {
            int i = r * 256 + tid;
            int kk = i & 31;
            int mm = i >> 5;
            int m = m0 + mm;
            float v = 0.0f;
            if (m < N_NODES) {
                v = r1[(long long)m * F_HID + k0 + kk];
            }
            Rs[kk][mm] = v;
        }
#pragma unroll
        for (int r = 0; r < 8; ++r) {
            int i = r * 256 + tid;
            int wk = i >> 6;
            int wn = i & 63;
            Ws[wk][wn] = W2[(k0 + wk) * F_OUT + wn];
        }
        __syncthreads();
#pragma unroll
        for (int k = 0; k < 32; ++k) {
            float a[4];
            float b[4];
#pragma unroll
            for (int i = 0; i < 4; ++i) a[i] = Rs[k][ty * 4 + i];
#pragma unroll
            for (int j = 0; j < 4; ++j) b[j] = Ws[k][tx * 4 + j];
#pragma unroll
            for (int i = 0; i < 4; ++i) {
#pragma unroll
                for (int j = 0; j < 4; ++j) acc[i][j] += a[i] * b[j];
            }
        }
        __syncthreads();
    }
#pragma unroll
    for (int i = 0; i < 4; ++i) {
        int m = m0 + ty * 4 + i;
        if (m < N_NODES) {
            float4 o;
            o.x = acc[i][0]; o.y = acc[i][1]; o.z = acc[i][2]; o.w = acc[i][3];
            *(float4*)(h2 + (long long)m * F_OUT + tx * 4) = o;
        }
    }
}

// ---- agg2 CSR + final epilogue fused: one wave per node, lane owns 1 feature.
// out[d] = dinv[d]*sum dinv[s]*h2[s] + dinv[d]^2*h2[d] + b2, in input float format ----
__global__ void g7_agg2(const int* rowptr, const int* csr, const float* dinv,
                        const float* h2, const float* b2, const int* fflag,
                        void* out) {
    int node = blockIdx.x * 4 + (threadIdx.x >> 6);
    int lane = threadIdx.x & 63;
    if (node < N_NODES) {
        int beg = rowptr[node];
        int end = rowptr[node + 1];
        float acc = 0.0f;
        for (int j = beg; j < end; j = j + 1) {
            int s = csr[j];
            acc = acc + h2[(long long)s * 64 + lane] * dinv[s];
        }
        float di = dinv[node];
        float v = acc * di + h2[(long long)node * 64 + lane] * di * di + b2[lane];
        long long oi = (long long)node * 64 + lane;
        if (fflag[0] == 1) {
            ((unsigned short*)out)[oi] = g7_f2bf(v);
        } else {
            ((float*)out)[oi] = v;
        }
    }
}

extern "C" void kernel_launch(void* const* d_in, const int* in_sizes, int n_in,
                              void* d_out, int out_size, void* d_ws, size_t ws_size,
                              hipStream_t stream) {
    const void* x     = d_in[0];
    const int* ei_raw = (const int*)d_in[1];
    const void* W1    = d_in[2];
    const void* b1    = d_in[3];
    const void* W2    = d_in[4];
    const void* b2    = d_in[5];

    const int NBLK = (N_NODES + 255) / 256;   // 391

    // workspace layout (byte offsets, 16B-aligned), end ~151.2 MB:
    char* ws = (char*)d_ws;
    int*   deg    = (int*)(ws + 0);            //    400,000 B
    int*   iflag  = (int*)(ws + 409600);       //          4 B
    int*   fflag  = (int*)(ws + 409616);       //          4 B
    int*   bsum   = (int*)(ws + 409632);       //      1,564 B
    int*   boff   = (int*)(ws + 412800);       //      1,564 B
    float* dinv   = (float*)(ws + 524288);     //    400,000 B
    float* W1f    = (float*)(ws + 1048576);    //    262,144 B
    float* b1f    = (float*)(ws + 1310720);    //        512 B
    float* W2f    = (float*)(ws + 1311232);    //     32,768 B
    float* b2f    = (float*)(ws + 1344000);    //        256 B
    int*   ei     = (int*)(ws + 2097152);      // 12,800,000 B
    int*   rowptr = (int*)(ws + 14897152);     //    400,004 B
    int*   cursor = (int*)(ws + 15298560);     //    400,000 B
    int*   csr    = (int*)(ws + 16777216);     //  6,400,000 B
    float* h1     = (float*)(ws + 23177216);   // 51,200,000 B
    float* r1     = (float*)(ws + 74377216);   // 51,200,000 B
    float* h2     = (float*)(ws + 125577216);  // 25,600,000 B

    g7_zero<<<(N_NODES + 255) / 256, 256, 0, stream>>>(deg, N_NODES);

    g7_iprobe<<<1, 64, 0, stream>>>(ei_raw, iflag);
    g7_fprobe<<<1, 64, 0, stream>>>((const unsigned int*)x, fflag);

    g7_pack<<<(2 * N_EDGES + 255) / 256, 256, 0, stream>>>(ei_raw, iflag, ei);

    g7_cvt<<<(F_IN * F_HID + 255) / 256, 256, 0, stream>>>(W1, fflag, W1f, F_IN * F_HID);
    g7_cvt<<<1, 128, 0, stream>>>(b1, fflag, b1f, F_HID);
    g7_cvt<<<(F_HID * F_OUT + 255) / 256, 256, 0, stream>>>(W2, fflag, W2f, F_HID * F_OUT);
    g7_cvt<<<1, 64, 0, stream>>>(b2, fflag, b2f, F_OUT);

    g7_deg<<<(N_EDGES + 255) / 256, 256, 0, stream>>>(ei, deg);
    g7_dinv<<<(N_NODES + 255) / 256, 256, 0, stream>>>(deg, dinv);

    // CSR build
    g7_bsum<<<NBLK, 256, 0, stream>>>(deg, bsum);
    g7_bscan<<<1, 64, 0, stream>>>(bsum, boff, NBLK, rowptr);
    g7_scan<<<NBLK, 256, 0, stream>>>(deg, boff, rowptr, cursor);
    g7_scatter<<<(N_EDGES + 255) / 256, 256, 0, stream>>>(ei, cursor, csr);

    g7_gemm1<<<(N_NODES + 63) / 64, 256, 0, stream>>>(x, fflag, W1f, h1);

    g7_agg1<<<N_NODES / 4, 256, 0, stream>>>(rowptr, csr, dinv, h1, b1f, r1);

    g7_gemm2<<<(N_NODES + 63) / 64, 256, 0, stream>>>(r1, W2f, h2);

    g7_agg2<<<N_NODES / 4, 256, 0, stream>>>(rowptr, csr, dinv, h2, b2f, fflag, d_out);
}